// Round 1
// baseline (884.284 us; speedup 1.0000x reference)
//
#include <hip/hip_runtime.h>
#include <hip/hip_bf16.h>

#define NND 6890
#define NED 41340

typedef __bf16 bf16x8 __attribute__((ext_vector_type(8)));
typedef float f32x4 __attribute__((ext_vector_type(4)));
typedef unsigned short u16x8 __attribute__((ext_vector_type(8)));

__device__ inline unsigned short f32_bf16(float f) {
  unsigned int u = __float_as_uint(f);
  unsigned int r = (u + 0x7FFFu + ((u >> 16) & 1u)) >> 16;
  return (unsigned short)r;
}
__device__ inline float elu_f(float v) { return v > 0.f ? v : (expf(v) - 1.f); }

__global__ void zero_int_kernel(int* p, int n) {
  int i = blockIdx.x * blockDim.x + threadIdx.x;
  if (i < n) p[i] = 0;
}

__global__ void edge_prep_kernel(const int* __restrict__ erow, const float* __restrict__ pseudo,
                                 float* __restrict__ ew, int* __restrict__ ek,
                                 int* __restrict__ deg, int E) {
  int e = blockIdx.x * blockDim.x + threadIdx.x;
  if (e >= E) return;
  float p0 = pseudo[2 * e + 0] * 4.0f;
  float p1 = pseudo[2 * e + 1] * 4.0f;
  int i0 = (int)floorf(p0); i0 = i0 < 0 ? 0 : (i0 > 3 ? 3 : i0);
  int i1 = (int)floorf(p1); i1 = i1 < 0 ? 0 : (i1 > 3 ? 3 : i1);
  float f0 = p0 - (float)i0, f1 = p1 - (float)i1;
  ew[4 * e + 0] = (1.f - f0) * (1.f - f1);
  ew[4 * e + 1] = f0 * (1.f - f1);
  ew[4 * e + 2] = (1.f - f0) * f1;
  ew[4 * e + 3] = f0 * f1;
  int b = i0 + 5 * i1;
  ek[4 * e + 0] = b; ek[4 * e + 1] = b + 1; ek[4 * e + 2] = b + 5; ek[4 * e + 3] = b + 6;
  atomicAdd(&deg[erow[e]], 1);
}

__global__ void scan_kernel(const int* __restrict__ deg, int* __restrict__ rowptr,
                            int* __restrict__ cursor, float* __restrict__ deginv, int n) {
  __shared__ int part[1024];
  int t = threadIdx.x;
  int CH = (n + 1023) >> 10;
  int base = t * CH;
  int s = 0;
  for (int j = 0; j < CH; ++j) { int i = base + j; if (i < n) s += deg[i]; }
  part[t] = s;
  __syncthreads();
  for (int off = 1; off < 1024; off <<= 1) {
    int v = (t >= off) ? part[t - off] : 0;
    __syncthreads();
    part[t] += v;
    __syncthreads();
  }
  int run = (t == 0) ? 0 : part[t - 1];
  for (int j = 0; j < CH; ++j) {
    int i = base + j;
    if (i < n) {
      rowptr[i] = run; cursor[i] = run;
      int d = deg[i];
      deginv[i] = 1.0f / fmaxf((float)d, 1.0f);
      run += d;
    }
  }
  if (t == 1023) rowptr[n] = part[1023];
}

__global__ void csr_fill_kernel(const int* __restrict__ erow, int* __restrict__ cursor,
                                int* __restrict__ csr, int E) {
  int e = blockIdx.x * blockDim.x + threadIdx.x;
  if (e >= E) return;
  int slot = atomicAdd(&cursor[erow[e]], 1);
  csr[slot] = e;
}

// B[r, k*Fin+i] = deginv[r] * sum_{edges into r} w[e,s(k)] * x[col[e], i]; last Fin cols = x[r]
__global__ void b_build_kernel(const float* __restrict__ x, const int* __restrict__ ecol,
                               const float* __restrict__ ew, const int* __restrict__ ek,
                               const int* __restrict__ rowptr, const int* __restrict__ csr,
                               const float* __restrict__ deginv,
                               float* __restrict__ B, int Fin) {
  extern __shared__ float lds[];  // 26*Fin floats
  int r = blockIdx.x;
  int T = blockDim.x;  // 4*Fin
  int tid = threadIdx.x;
  int nb = 25 * Fin;
  for (int j = tid; j < nb; j += T) lds[j] = 0.f;
  if (tid < Fin) lds[nb + tid] = x[(size_t)r * Fin + tid];
  __syncthreads();
  int p0 = rowptr[r], p1 = rowptr[r + 1];
  int s = tid / Fin;
  int i = tid - s * Fin;
  for (int p = p0; p < p1; ++p) {
    int e = csr[p];
    int c = ecol[e];
    float wv = ew[4 * e + s];
    int k = ek[4 * e + s];
    float xv = x[(size_t)c * Fin + i];
    lds[k * Fin + i] += wv * xv;
    __syncthreads();
  }
  float dinv = deginv[r];
  int tot = nb + Fin;
  for (int j = tid; j < tot; j += T) {
    float v = lds[j];
    if (j < nb) v *= dinv;
    B[(size_t)r * tot + j] = v;
  }
}

// C = elu(A[M,Kd] @ W[Kd,F] + bias), out f32 or bf16. Kd % 32 == 0.
template <int BN, int TN>
__global__ __launch_bounds__(256) void gemm_f32_elu_kernel(
    const float* __restrict__ A, const float* __restrict__ W,
    const float* __restrict__ bias, float* __restrict__ outF,
    unsigned short* __restrict__ outB, int M, int Kd, int F) {
  constexpr int TM = 4;
  constexpr int BM = 64;
  constexpr int BK = 32;
  __shared__ float As[BM][BK + 1];
  __shared__ float Ws[BK][BN];
  int tid = threadIdx.x;
  int tc = tid & 15, tr = tid >> 4;
  int row0 = blockIdx.y * BM;
  int col0 = blockIdx.x * BN;
  float acc[TM][TN];
  for (int a = 0; a < TM; ++a)
    for (int b = 0; b < TN; ++b) acc[a][b] = 0.f;
  for (int kb = 0; kb < Kd; kb += BK) {
    for (int idx = tid; idx < BM * BK; idx += 256) {
      int rr = idx >> 5, kk = idx & 31;
      int gr = row0 + rr;
      As[rr][kk] = (gr < M) ? A[(size_t)gr * Kd + kb + kk] : 0.f;
    }
    for (int idx = tid; idx < BK * BN; idx += 256) {
      int kk = idx / BN, cc = idx % BN;
      int gc = col0 + cc;
      Ws[kk][cc] = (gc < F) ? W[(size_t)(kb + kk) * F + gc] : 0.f;
    }
    __syncthreads();
    for (int kk = 0; kk < BK; ++kk) {
      float wv[TN];
#pragma unroll
      for (int b = 0; b < TN; ++b) wv[b] = Ws[kk][tc * TN + b];
#pragma unroll
      for (int a = 0; a < TM; ++a) {
        float av = As[tr * TM + a][kk];
#pragma unroll
        for (int b = 0; b < TN; ++b) acc[a][b] += av * wv[b];
      }
    }
    __syncthreads();
  }
#pragma unroll
  for (int a = 0; a < TM; ++a) {
    int gr = row0 + tr * TM + a;
    if (gr >= M) continue;
#pragma unroll
    for (int b = 0; b < TN; ++b) {
      int gc = col0 + tc * TN + b;
      if (gc >= F) continue;
      float v = elu_f(acc[a][b] + bias[gc]);
      if (outB) outB[(size_t)gr * F + gc] = f32_bf16(v);
      else outF[(size_t)gr * F + gc] = v;
    }
  }
}

// W2 [K=256, N] f32  ->  Wt [N, K] bf16
__global__ void w2_cast_transpose_kernel(const float* __restrict__ W2,
                                         unsigned short* __restrict__ Wt, int K, int N) {
  __shared__ float t[32][33];
  int c0 = blockIdx.x * 32, k0 = blockIdx.y * 32;
  int tx = threadIdx.x, ty = threadIdx.y;  // 32 x 8
  for (int j = ty; j < 32; j += 8) {
    int gk = k0 + j, gc = c0 + tx;
    t[j][tx] = (gk < K && gc < N) ? W2[(size_t)gk * N + gc] : 0.f;
  }
  __syncthreads();
  for (int j = ty; j < 32; j += 8) {
    int gc = c0 + j, gk = k0 + tx;
    if (gc < N && gk < K) Wt[(size_t)gc * K + gk] = f32_bf16(t[tx][j]);
  }
}

// C[M,N] = A[M,256] @ Bt[N,256]^T + bias ;  bf16 in, f32 out
__global__ __launch_bounds__(256) void gemm_bf16_mfma_kernel(
    const unsigned short* __restrict__ A, const unsigned short* __restrict__ Bt,
    const float* __restrict__ bias, float* __restrict__ C, int M, int N) {
  constexpr int K = 256, BK = 32;
  __shared__ __align__(16) unsigned short As[128][40];
  __shared__ __align__(16) unsigned short Bs[128][40];
  int tid = threadIdx.x;
  int wave = tid >> 6, lane = tid & 63;
  int wm = wave >> 1, wn = wave & 1;
  int row0 = blockIdx.y * 128;
  int col0 = blockIdx.x * 128;
  f32x4 acc[4][4];
  for (int m = 0; m < 4; ++m)
    for (int n = 0; n < 4; ++n)
      for (int q = 0; q < 4; ++q) acc[m][n][q] = 0.f;
  int g = lane >> 4, r = lane & 15;
  for (int kb = 0; kb < K; kb += BK) {
#pragma unroll
    for (int rep = 0; rep < 2; ++rep) {
      int idx = tid + rep * 256;   // 0..511
      int rr = idx >> 2, ch = idx & 3;
      u16x8 va = {0, 0, 0, 0, 0, 0, 0, 0};
      int ga = row0 + rr;
      if (ga < M) va = *(const u16x8*)(A + (size_t)ga * K + kb + ch * 8);
      *(u16x8*)&As[rr][ch * 8] = va;
      u16x8 vb = {0, 0, 0, 0, 0, 0, 0, 0};
      int gb = col0 + rr;
      if (gb < N) vb = *(const u16x8*)(Bt + (size_t)gb * K + kb + ch * 8);
      *(u16x8*)&Bs[rr][ch * 8] = vb;
    }
    __syncthreads();
    bf16x8 fa[4], fb[4];
#pragma unroll
    for (int m = 0; m < 4; ++m) fa[m] = *(const bf16x8*)&As[wm * 64 + m * 16 + r][g * 8];
#pragma unroll
    for (int n = 0; n < 4; ++n) fb[n] = *(const bf16x8*)&Bs[wn * 64 + n * 16 + r][g * 8];
#pragma unroll
    for (int m = 0; m < 4; ++m)
#pragma unroll
      for (int n = 0; n < 4; ++n)
        acc[m][n] = __builtin_amdgcn_mfma_f32_16x16x32_bf16(fa[m], fb[n], acc[m][n], 0, 0, 0);
    __syncthreads();
  }
#pragma unroll
  for (int n = 0; n < 4; ++n) {
    int gc = col0 + wn * 64 + n * 16 + r;
    if (gc >= N) continue;
    float bv = bias[gc];
#pragma unroll
    for (int m = 0; m < 4; ++m) {
      int gr0 = row0 + wm * 64 + m * 16 + g * 4;
#pragma unroll
      for (int q = 0; q < 4; ++q) {
        int gr = gr0 + q;
        if (gr < M) C[(size_t)gr * N + gc] = acc[m][n][q] + bv;
      }
    }
  }
}

// in-place row log-softmax; row staged in LDS (N floats)
__global__ __launch_bounds__(256) void log_softmax_kernel(float* __restrict__ out, int N) {
  extern __shared__ float rowbuf[];
  __shared__ float red[256];
  int rIdx = blockIdx.x;
  float* p = out + (size_t)rIdx * N;
  float m = -1e30f;
  for (int c = threadIdx.x; c < N; c += 256) {
    float v = p[c];
    rowbuf[c] = v;
    m = fmaxf(m, v);
  }
  red[threadIdx.x] = m;
  __syncthreads();
  for (int off = 128; off > 0; off >>= 1) {
    if (threadIdx.x < off) red[threadIdx.x] = fmaxf(red[threadIdx.x], red[threadIdx.x + off]);
    __syncthreads();
  }
  m = red[0];
  __syncthreads();
  float s = 0.f;
  for (int c = threadIdx.x; c < N; c += 256) s += expf(rowbuf[c] - m);
  red[threadIdx.x] = s;
  __syncthreads();
  for (int off = 128; off > 0; off >>= 1) {
    if (threadIdx.x < off) red[threadIdx.x] += red[threadIdx.x + off];
    __syncthreads();
  }
  float lse = m + logf(red[0]);
  for (int c = threadIdx.x; c < N; c += 256) p[c] = rowbuf[c] - lse;
}

extern "C" void kernel_launch(void* const* d_in, const int* in_sizes, int n_in,
                              void* d_out, int out_size, void* d_ws, size_t ws_size,
                              hipStream_t stream) {
  const int N = NND, E = NED;
  const float* x      = (const float*)d_in[0];
  const int*   ei     = (const int*)d_in[1];
  const float* pseudo = (const float*)d_in[2];
  const float* W_lin  = (const float*)d_in[3];
  const float* b_lin  = (const float*)d_in[4];
  const float* w1  = (const float*)d_in[5];
  const float* r1  = (const float*)d_in[6];
  const float* bi1 = (const float*)d_in[7];
  const float* w2  = (const float*)d_in[8];
  const float* r2  = (const float*)d_in[9];
  const float* bi2 = (const float*)d_in[10];
  const float* w3  = (const float*)d_in[11];
  const float* r3  = (const float*)d_in[12];
  const float* bi3 = (const float*)d_in[13];
  const float* W1  = (const float*)d_in[14];
  const float* b1  = (const float*)d_in[15];
  const float* W2  = (const float*)d_in[16];
  const float* b2  = (const float*)d_in[17];
  const int* erow = ei;
  const int* ecol = ei + E;

  // Scratch carved out of d_out (dead before the final GEMM overwrites all of d_out)
  char* scratch = (char*)d_out;
  size_t off = 0;
  auto alloc = [&](size_t bytes) -> void* {
    void* p = scratch + off;
    off = (off + bytes + 255) & ~(size_t)255;
    return p;
  };
  float* Bbuf   = (float*)alloc((size_t)N * 1664 * 4);
  float* h0     = (float*)alloc((size_t)N * 16 * 4);
  float* h1     = (float*)alloc((size_t)N * 32 * 4);
  float* h2     = (float*)alloc((size_t)N * 64 * 4);
  float* h3     = (float*)alloc((size_t)N * 128 * 4);
  float* Waug   = (float*)alloc((size_t)1664 * 128 * 4);
  float* ew     = (float*)alloc((size_t)E * 4 * 4);
  int*   ek     = (int*)alloc((size_t)E * 4 * 4);
  int*   deg    = (int*)alloc((size_t)N * 4);
  float* deginv = (float*)alloc((size_t)N * 4);
  int*   rowptr = (int*)alloc((size_t)(N + 1) * 4);
  int*   cursor = (int*)alloc((size_t)N * 4);
  int*   csr    = (int*)alloc((size_t)E * 4);

  // Buffers alive during the final GEMM go in d_ws
  unsigned short* h4b = (unsigned short*)d_ws;                            // N*256 bf16
  unsigned short* W2t = (unsigned short*)((char*)d_ws + (size_t)N * 256 * 2);  // N*256 bf16

  // ---- graph prep: degrees, CSR, edge weights ----
  zero_int_kernel<<<(N + 255) / 256, 256, 0, stream>>>(deg, N);
  edge_prep_kernel<<<(E + 255) / 256, 256, 0, stream>>>(erow, pseudo, ew, ek, deg, E);
  scan_kernel<<<1, 1024, 0, stream>>>(deg, rowptr, cursor, deginv, N);
  csr_fill_kernel<<<(E + 255) / 256, 256, 0, stream>>>(erow, cursor, csr, E);

  // ---- stage 0: h0 = elu(x @ W_lin + b_lin) ----
  gemm_f32_elu_kernel<16, 1><<<dim3(1, 108), 256, 0, stream>>>(x, W_lin, b_lin, h0, nullptr, N, 544, 16);

  // ---- spline layer 1 (16 -> 32) ----
  hipMemcpyAsync(Waug, w1, (size_t)25 * 16 * 32 * 4, hipMemcpyDeviceToDevice, stream);
  hipMemcpyAsync(Waug + 25 * 16 * 32, r1, (size_t)16 * 32 * 4, hipMemcpyDeviceToDevice, stream);
  b_build_kernel<<<N, 64, 26 * 16 * 4, stream>>>(h0, ecol, ew, ek, rowptr, csr, deginv, Bbuf, 16);
  gemm_f32_elu_kernel<32, 2><<<dim3(1, 108), 256, 0, stream>>>(Bbuf, Waug, bi1, h1, nullptr, N, 416, 32);

  // ---- spline layer 2 (32 -> 64) ----
  hipMemcpyAsync(Waug, w2, (size_t)25 * 32 * 64 * 4, hipMemcpyDeviceToDevice, stream);
  hipMemcpyAsync(Waug + 25 * 32 * 64, r2, (size_t)32 * 64 * 4, hipMemcpyDeviceToDevice, stream);
  b_build_kernel<<<N, 128, 26 * 32 * 4, stream>>>(h1, ecol, ew, ek, rowptr, csr, deginv, Bbuf, 32);
  gemm_f32_elu_kernel<64, 4><<<dim3(1, 108), 256, 0, stream>>>(Bbuf, Waug, bi2, h2, nullptr, N, 832, 64);

  // ---- spline layer 3 (64 -> 128) ----
  hipMemcpyAsync(Waug, w3, (size_t)25 * 64 * 128 * 4, hipMemcpyDeviceToDevice, stream);
  hipMemcpyAsync(Waug + 25 * 64 * 128, r3, (size_t)64 * 128 * 4, hipMemcpyDeviceToDevice, stream);
  b_build_kernel<<<N, 256, 26 * 64 * 4, stream>>>(h2, ecol, ew, ek, rowptr, csr, deginv, Bbuf, 64);
  gemm_f32_elu_kernel<64, 4><<<dim3(2, 108), 256, 0, stream>>>(Bbuf, Waug, bi3, h3, nullptr, N, 1664, 128);

  // ---- stage 4: h4 = elu(h3 @ W1 + b1), written as bf16 ----
  gemm_f32_elu_kernel<64, 4><<<dim3(4, 108), 256, 0, stream>>>(h3, W1, b1, nullptr, h4b, N, 128, 256);

  // ---- W2 -> bf16 transposed ----
  w2_cast_transpose_kernel<<<dim3(216, 8), dim3(32, 8), 0, stream>>>(W2, W2t, 256, N);

  // ---- logits = h4 @ W2 + b2 (bf16 MFMA, f32 out into d_out) ----
  gemm_bf16_mfma_kernel<<<dim3(54, 54), 256, 0, stream>>>(h4b, W2t, b2, (float*)d_out, N, N);

  // ---- in-place log-softmax over rows ----
  log_softmax_kernel<<<N, 256, (size_t)N * 4, stream>>>((float*)d_out, N);

  (void)in_sizes; (void)n_in; (void)out_size; (void)ws_size;
}

// Round 2
// 432.035 us; speedup vs baseline: 2.0468x; 2.0468x over previous
//
#include <hip/hip_runtime.h>
#include <hip/hip_bf16.h>

#define NND 6890
#define NED 41340

typedef __bf16 bf16x8 __attribute__((ext_vector_type(8)));
typedef float f32x4 __attribute__((ext_vector_type(4)));
typedef unsigned short u16x4 __attribute__((ext_vector_type(4)));
typedef unsigned short u16x8 __attribute__((ext_vector_type(8)));

__device__ inline unsigned short f32_bf16(float f) {
  unsigned int u = __float_as_uint(f);
  unsigned int r = (u + 0x7FFFu + ((u >> 16) & 1u)) >> 16;
  return (unsigned short)r;
}
__device__ inline void split2(float v, unsigned short& hi, unsigned short& lo) {
  unsigned short h = f32_bf16(v);
  float hf = __uint_as_float((unsigned int)h << 16);
  hi = h;
  lo = f32_bf16(v - hf);
}
__device__ inline float elu_f(float v) { return v > 0.f ? v : (expf(v) - 1.f); }

__global__ void zero_int_kernel(int* p, int n) {
  int i = blockIdx.x * blockDim.x + threadIdx.x;
  if (i < n) p[i] = 0;
}

__global__ void edge_prep_kernel(const int* __restrict__ erow, const float* __restrict__ pseudo,
                                 float* __restrict__ ew, int* __restrict__ ek,
                                 int* __restrict__ deg, int E) {
  int e = blockIdx.x * blockDim.x + threadIdx.x;
  if (e >= E) return;
  float p0 = pseudo[2 * e + 0] * 4.0f;
  float p1 = pseudo[2 * e + 1] * 4.0f;
  int i0 = (int)floorf(p0); i0 = i0 < 0 ? 0 : (i0 > 3 ? 3 : i0);
  int i1 = (int)floorf(p1); i1 = i1 < 0 ? 0 : (i1 > 3 ? 3 : i1);
  float f0 = p0 - (float)i0, f1 = p1 - (float)i1;
  ew[4 * e + 0] = (1.f - f0) * (1.f - f1);
  ew[4 * e + 1] = f0 * (1.f - f1);
  ew[4 * e + 2] = (1.f - f0) * f1;
  ew[4 * e + 3] = f0 * f1;
  int b = i0 + 5 * i1;
  ek[4 * e + 0] = b; ek[4 * e + 1] = b + 1; ek[4 * e + 2] = b + 5; ek[4 * e + 3] = b + 6;
  atomicAdd(&deg[erow[e]], 1);
}

__global__ void scan_kernel(const int* __restrict__ deg, int* __restrict__ rowptr,
                            int* __restrict__ cursor, float* __restrict__ deginv, int n) {
  __shared__ int part[1024];
  int t = threadIdx.x;
  int CH = (n + 1023) >> 10;
  int base = t * CH;
  int s = 0;
  for (int j = 0; j < CH; ++j) { int i = base + j; if (i < n) s += deg[i]; }
  part[t] = s;
  __syncthreads();
  for (int off = 1; off < 1024; off <<= 1) {
    int v = (t >= off) ? part[t - off] : 0;
    __syncthreads();
    part[t] += v;
    __syncthreads();
  }
  int run = (t == 0) ? 0 : part[t - 1];
  for (int j = 0; j < CH; ++j) {
    int i = base + j;
    if (i < n) {
      rowptr[i] = run; cursor[i] = run;
      int d = deg[i];
      deginv[i] = 1.0f / fmaxf((float)d, 1.0f);
      run += d;
    }
  }
  if (t == 1023) rowptr[n] = part[1023];
}

__global__ void csr_fill_kernel(const int* __restrict__ erow, int* __restrict__ cursor,
                                int* __restrict__ csr, int E) {
  int e = blockIdx.x * blockDim.x + threadIdx.x;
  if (e >= E) return;
  int slot = atomicAdd(&cursor[erow[e]], 1);
  csr[slot] = e;
}

// B[r, k*Fin+i] = deginv[r] * sum_{edges into r} w[e,s(k)] * x[col[e], i]; last Fin cols = x[r]
__global__ void b_build_kernel(const float* __restrict__ x, const int* __restrict__ ecol,
                               const float* __restrict__ ew, const int* __restrict__ ek,
                               const int* __restrict__ rowptr, const int* __restrict__ csr,
                               const float* __restrict__ deginv,
                               float* __restrict__ B, int Fin) {
  extern __shared__ float lds[];  // 26*Fin floats
  int r = blockIdx.x;
  int T = blockDim.x;  // 4*Fin
  int tid = threadIdx.x;
  int nb = 25 * Fin;
  for (int j = tid; j < nb; j += T) lds[j] = 0.f;
  if (tid < Fin) lds[nb + tid] = x[(size_t)r * Fin + tid];
  __syncthreads();
  int p0 = rowptr[r], p1 = rowptr[r + 1];
  int s = tid / Fin;
  int i = tid - s * Fin;
  for (int p = p0; p < p1; ++p) {
    int e = csr[p];
    int c = ecol[e];
    float wv = ew[4 * e + s];
    int k = ek[4 * e + s];
    float xv = x[(size_t)c * Fin + i];
    lds[k * Fin + i] += wv * xv;
    __syncthreads();
  }
  float dinv = deginv[r];
  int tot = nb + Fin;
  for (int j = tid; j < tot; j += T) {
    float v = lds[j];
    if (j < nb) v *= dinv;
    B[(size_t)r * tot + j] = v;
  }
}

// W [K,F] f32 -> Th/Tl [F, ldt] bf16 hi/lo at column offset koff (transposed)
__global__ void split_transpose_kernel(const float* __restrict__ W,
                                       unsigned short* __restrict__ Th,
                                       unsigned short* __restrict__ Tl,
                                       int K, int F, int ldt, int koff) {
  __shared__ float t[32][33];
  int k0 = blockIdx.y * 32, c0 = blockIdx.x * 32;
  int tx = threadIdx.x, ty = threadIdx.y;  // 32 x 8
  for (int j = ty; j < 32; j += 8) {
    int gk = k0 + j, gc = c0 + tx;
    t[j][tx] = (gk < K && gc < F) ? W[(size_t)gk * F + gc] : 0.f;
  }
  __syncthreads();
  for (int j = ty; j < 32; j += 8) {
    int gc = c0 + j, gk = k0 + tx;
    if (gc < F && gk < K) {
      unsigned short h, l;
      split2(t[tx][j], h, l);
      Th[(size_t)gc * ldt + koff + gk] = h;
      Tl[(size_t)gc * ldt + koff + gk] = l;
    }
  }
}

// C = elu(A[M,Kd] @ W + bias) with f32 accuracy via bf16x3 split MFMA.
// A f32 row-major; W pre-split transposed: Wth/Wtl [F, Kd] bf16.
// Kd % 32 == 0, F % BN == 0. Output f32 (outF) or bf16 (outB).
template <int BN>
__global__ __launch_bounds__(256) void gemm_x3_kernel(
    const float* __restrict__ A, const unsigned short* __restrict__ Wth,
    const unsigned short* __restrict__ Wtl, const float* __restrict__ bias,
    float* __restrict__ outF, unsigned short* __restrict__ outB,
    int M, int Kd, int F) {
  constexpr int BK = 32;
  constexpr int NF = BN / 16;
  constexpr int WU = (BK * BN) / 4;        // u16x4 units in W tile
  constexpr int WREP = (WU + 255) / 256;
  __shared__ __align__(16) unsigned short Ah[2][64][40];
  __shared__ __align__(16) unsigned short Al[2][64][40];
  __shared__ __align__(16) unsigned short Wh[2][BN][40];
  __shared__ __align__(16) unsigned short Wl[2][BN][40];
  int tid = threadIdx.x;
  int wave = tid >> 6, lane = tid & 63;
  int g = lane >> 4, r = lane & 15;
  int row0 = blockIdx.y * 64;
  int col0 = blockIdx.x * BN;

  f32x4 acc[NF];
#pragma unroll
  for (int n = 0; n < NF; ++n)
#pragma unroll
    for (int q = 0; q < 4; ++q) acc[n][q] = 0.f;

  f32x4 ra[2];
  u16x4 rwh[WREP], rwl[WREP];

  auto loadTiles = [&](int kb) {
#pragma unroll
    for (int rep = 0; rep < 2; ++rep) {
      int u = tid + rep * 256;
      int rr = u >> 3, kq = (u & 7) * 4;
      int gr = row0 + rr;
      f32x4 v = {0.f, 0.f, 0.f, 0.f};
      if (gr < M) v = *(const f32x4*)(A + (size_t)gr * Kd + kb + kq);
      ra[rep] = v;
    }
#pragma unroll
    for (int rep = 0; rep < WREP; ++rep) {
      int u = tid + rep * 256;
      if (u < WU) {
        int cc = u >> 3, kq = (u & 7) * 4;
        rwh[rep] = *(const u16x4*)(Wth + (size_t)(col0 + cc) * Kd + kb + kq);
        rwl[rep] = *(const u16x4*)(Wtl + (size_t)(col0 + cc) * Kd + kb + kq);
      }
    }
  };
  auto writeLDS = [&](int buf) {
#pragma unroll
    for (int rep = 0; rep < 2; ++rep) {
      int u = tid + rep * 256;
      int rr = u >> 3, kq = (u & 7) * 4;
      u16x4 h, l;
#pragma unroll
      for (int j = 0; j < 4; ++j) {
        unsigned short hh, ll;
        split2(ra[rep][j], hh, ll);
        h[j] = hh; l[j] = ll;
      }
      *(u16x4*)&Ah[buf][rr][kq] = h;
      *(u16x4*)&Al[buf][rr][kq] = l;
    }
#pragma unroll
    for (int rep = 0; rep < WREP; ++rep) {
      int u = tid + rep * 256;
      if (u < WU) {
        int cc = u >> 3, kq = (u & 7) * 4;
        *(u16x4*)&Wh[buf][cc][kq] = rwh[rep];
        *(u16x4*)&Wl[buf][cc][kq] = rwl[rep];
      }
    }
  };

  int nt = Kd / BK;
  loadTiles(0);
  writeLDS(0);
  __syncthreads();
  for (int t = 0; t < nt; ++t) {
    int cur = t & 1;
    if (t + 1 < nt) loadTiles((t + 1) * BK);
    bf16x8 fah = *(const bf16x8*)&Ah[cur][wave * 16 + r][g * 8];
    bf16x8 fal = *(const bf16x8*)&Al[cur][wave * 16 + r][g * 8];
#pragma unroll
    for (int n = 0; n < NF; ++n) {
      bf16x8 fbh = *(const bf16x8*)&Wh[cur][n * 16 + r][g * 8];
      bf16x8 fbl = *(const bf16x8*)&Wl[cur][n * 16 + r][g * 8];
      acc[n] = __builtin_amdgcn_mfma_f32_16x16x32_bf16(fah, fbh, acc[n], 0, 0, 0);
      acc[n] = __builtin_amdgcn_mfma_f32_16x16x32_bf16(fal, fbh, acc[n], 0, 0, 0);
      acc[n] = __builtin_amdgcn_mfma_f32_16x16x32_bf16(fah, fbl, acc[n], 0, 0, 0);
    }
    if (t + 1 < nt) writeLDS(cur ^ 1);
    __syncthreads();
  }
#pragma unroll
  for (int n = 0; n < NF; ++n) {
    int gc = col0 + n * 16 + r;
    float bv = bias[gc];
#pragma unroll
    for (int q = 0; q < 4; ++q) {
      int gr = row0 + wave * 16 + g * 4 + q;
      if (gr < M) {
        float v = elu_f(acc[n][q] + bv);
        if (outB) outB[(size_t)gr * F + gc] = f32_bf16(v);
        else outF[(size_t)gr * F + gc] = v;
      }
    }
  }
}

// W2 [K=256, N] f32  ->  Wt [N, K] bf16
__global__ void w2_cast_transpose_kernel(const float* __restrict__ W2,
                                         unsigned short* __restrict__ Wt, int K, int N) {
  __shared__ float t[32][33];
  int c0 = blockIdx.x * 32, k0 = blockIdx.y * 32;
  int tx = threadIdx.x, ty = threadIdx.y;  // 32 x 8
  for (int j = ty; j < 32; j += 8) {
    int gk = k0 + j, gc = c0 + tx;
    t[j][tx] = (gk < K && gc < N) ? W2[(size_t)gk * N + gc] : 0.f;
  }
  __syncthreads();
  for (int j = ty; j < 32; j += 8) {
    int gc = c0 + j, gk = k0 + tx;
    if (gc < N && gk < K) Wt[(size_t)gc * K + gk] = f32_bf16(t[tx][j]);
  }
}

// C[M,N] = A[M,256] @ Bt[N,256]^T + bias ;  bf16 in, f32 out
__global__ __launch_bounds__(256) void gemm_bf16_mfma_kernel(
    const unsigned short* __restrict__ A, const unsigned short* __restrict__ Bt,
    const float* __restrict__ bias, float* __restrict__ C, int M, int N) {
  constexpr int K = 256, BK = 32;
  __shared__ __align__(16) unsigned short As[128][40];
  __shared__ __align__(16) unsigned short Bs[128][40];
  int tid = threadIdx.x;
  int wave = tid >> 6, lane = tid & 63;
  int wm = wave >> 1, wn = wave & 1;
  int row0 = blockIdx.y * 128;
  int col0 = blockIdx.x * 128;
  f32x4 acc[4][4];
  for (int m = 0; m < 4; ++m)
    for (int n = 0; n < 4; ++n)
      for (int q = 0; q < 4; ++q) acc[m][n][q] = 0.f;
  int g = lane >> 4, r = lane & 15;
  for (int kb = 0; kb < K; kb += BK) {
#pragma unroll
    for (int rep = 0; rep < 2; ++rep) {
      int idx = tid + rep * 256;   // 0..511
      int rr = idx >> 2, ch = idx & 3;
      u16x8 va = {0, 0, 0, 0, 0, 0, 0, 0};
      int ga = row0 + rr;
      if (ga < M) va = *(const u16x8*)(A + (size_t)ga * K + kb + ch * 8);
      *(u16x8*)&As[rr][ch * 8] = va;
      u16x8 vb = {0, 0, 0, 0, 0, 0, 0, 0};
      int gb = col0 + rr;
      if (gb < N) vb = *(const u16x8*)(Bt + (size_t)gb * K + kb + ch * 8);
      *(u16x8*)&Bs[rr][ch * 8] = vb;
    }
    __syncthreads();
    bf16x8 fa[4], fb[4];
#pragma unroll
    for (int m = 0; m < 4; ++m) fa[m] = *(const bf16x8*)&As[wm * 64 + m * 16 + r][g * 8];
#pragma unroll
    for (int n = 0; n < 4; ++n) fb[n] = *(const bf16x8*)&Bs[wn * 64 + n * 16 + r][g * 8];
#pragma unroll
    for (int m = 0; m < 4; ++m)
#pragma unroll
      for (int n = 0; n < 4; ++n)
        acc[m][n] = __builtin_amdgcn_mfma_f32_16x16x32_bf16(fa[m], fb[n], acc[m][n], 0, 0, 0);
    __syncthreads();
  }
#pragma unroll
  for (int n = 0; n < 4; ++n) {
    int gc = col0 + wn * 64 + n * 16 + r;
    if (gc >= N) continue;
    float bv = bias[gc];
#pragma unroll
    for (int m = 0; m < 4; ++m) {
      int gr0 = row0 + wm * 64 + m * 16 + g * 4;
#pragma unroll
      for (int q = 0; q < 4; ++q) {
        int gr = gr0 + q;
        if (gr < M) C[(size_t)gr * N + gc] = acc[m][n][q] + bv;
      }
    }
  }
}

// in-place row log-softmax; row staged in LDS (N floats)
__global__ __launch_bounds__(256) void log_softmax_kernel(float* __restrict__ out, int N) {
  extern __shared__ float rowbuf[];
  __shared__ float red[256];
  int rIdx = blockIdx.x;
  float* p = out + (size_t)rIdx * N;
  float m = -1e30f;
  for (int c = threadIdx.x; c < N; c += 256) {
    float v = p[c];
    rowbuf[c] = v;
    m = fmaxf(m, v);
  }
  red[threadIdx.x] = m;
  __syncthreads();
  for (int off = 128; off > 0; off >>= 1) {
    if (threadIdx.x < off) red[threadIdx.x] = fmaxf(red[threadIdx.x], red[threadIdx.x + off]);
    __syncthreads();
  }
  m = red[0];
  __syncthreads();
  float s = 0.f;
  for (int c = threadIdx.x; c < N; c += 256) s += expf(rowbuf[c] - m);
  red[threadIdx.x] = s;
  __syncthreads();
  for (int off = 128; off > 0; off >>= 1) {
    if (threadIdx.x < off) red[threadIdx.x] += red[threadIdx.x + off];
    __syncthreads();
  }
  float lse = m + logf(red[0]);
  for (int c = threadIdx.x; c < N; c += 256) p[c] = rowbuf[c] - lse;
}

extern "C" void kernel_launch(void* const* d_in, const int* in_sizes, int n_in,
                              void* d_out, int out_size, void* d_ws, size_t ws_size,
                              hipStream_t stream) {
  const int N = NND, E = NED;
  const float* x      = (const float*)d_in[0];
  const int*   ei     = (const int*)d_in[1];
  const float* pseudo = (const float*)d_in[2];
  const float* W_lin  = (const float*)d_in[3];
  const float* b_lin  = (const float*)d_in[4];
  const float* w1  = (const float*)d_in[5];
  const float* r1  = (const float*)d_in[6];
  const float* bi1 = (const float*)d_in[7];
  const float* w2  = (const float*)d_in[8];
  const float* r2  = (const float*)d_in[9];
  const float* bi2 = (const float*)d_in[10];
  const float* w3  = (const float*)d_in[11];
  const float* r3  = (const float*)d_in[12];
  const float* bi3 = (const float*)d_in[13];
  const float* W1  = (const float*)d_in[14];
  const float* b1  = (const float*)d_in[15];
  const float* W2  = (const float*)d_in[16];
  const float* b2  = (const float*)d_in[17];
  const int* erow = ei;
  const int* ecol = ei + E;

  // Scratch carved out of d_out (dead before the final GEMM overwrites all of d_out)
  char* scratch = (char*)d_out;
  size_t off = 0;
  auto alloc = [&](size_t bytes) -> void* {
    void* p = scratch + off;
    off = (off + bytes + 255) & ~(size_t)255;
    return p;
  };
  float* Bbuf   = (float*)alloc((size_t)N * 1664 * 4);
  float* h0     = (float*)alloc((size_t)N * 16 * 4);
  float* h1     = (float*)alloc((size_t)N * 32 * 4);
  float* h2     = (float*)alloc((size_t)N * 64 * 4);
  float* h3     = (float*)alloc((size_t)N * 128 * 4);
  unsigned short* Wth = (unsigned short*)alloc((size_t)128 * 1664 * 2);
  unsigned short* Wtl = (unsigned short*)alloc((size_t)128 * 1664 * 2);
  float* ew     = (float*)alloc((size_t)E * 4 * 4);
  int*   ek     = (int*)alloc((size_t)E * 4 * 4);
  int*   deg    = (int*)alloc((size_t)N * 4);
  float* deginv = (float*)alloc((size_t)N * 4);
  int*   rowptr = (int*)alloc((size_t)(N + 1) * 4);
  int*   cursor = (int*)alloc((size_t)N * 4);
  int*   csr    = (int*)alloc((size_t)E * 4);

  // Buffers alive during the final GEMM go in d_ws
  unsigned short* h4b = (unsigned short*)d_ws;                                 // N*256 bf16
  unsigned short* W2t = (unsigned short*)((char*)d_ws + (size_t)N * 256 * 2);  // N*256 bf16

  dim3 tb32(32, 8);

  // ---- graph prep: degrees, CSR, edge weights ----
  zero_int_kernel<<<(N + 255) / 256, 256, 0, stream>>>(deg, N);
  edge_prep_kernel<<<(E + 255) / 256, 256, 0, stream>>>(erow, pseudo, ew, ek, deg, E);
  scan_kernel<<<1, 1024, 0, stream>>>(deg, rowptr, cursor, deginv, N);
  csr_fill_kernel<<<(E + 255) / 256, 256, 0, stream>>>(erow, cursor, csr, E);

  // ---- stage 0: h0 = elu(x @ W_lin + b_lin) ----
  split_transpose_kernel<<<dim3(1, 17), tb32, 0, stream>>>(W_lin, Wth, Wtl, 544, 16, 544, 0);
  gemm_x3_kernel<16><<<dim3(1, 108), 256, 0, stream>>>(x, Wth, Wtl, b_lin, h0, nullptr, N, 544, 16);

  // ---- spline layer 1 (16 -> 32), Kd = 416 ----
  split_transpose_kernel<<<dim3(1, 13), tb32, 0, stream>>>(w1, Wth, Wtl, 400, 32, 416, 0);
  split_transpose_kernel<<<dim3(1, 1),  tb32, 0, stream>>>(r1, Wth, Wtl, 16, 32, 416, 400);
  b_build_kernel<<<N, 64, 26 * 16 * 4, stream>>>(h0, ecol, ew, ek, rowptr, csr, deginv, Bbuf, 16);
  gemm_x3_kernel<32><<<dim3(1, 108), 256, 0, stream>>>(Bbuf, Wth, Wtl, bi1, h1, nullptr, N, 416, 32);

  // ---- spline layer 2 (32 -> 64), Kd = 832 ----
  split_transpose_kernel<<<dim3(2, 25), tb32, 0, stream>>>(w2, Wth, Wtl, 800, 64, 832, 0);
  split_transpose_kernel<<<dim3(2, 1),  tb32, 0, stream>>>(r2, Wth, Wtl, 32, 64, 832, 800);
  b_build_kernel<<<N, 128, 26 * 32 * 4, stream>>>(h1, ecol, ew, ek, rowptr, csr, deginv, Bbuf, 32);
  gemm_x3_kernel<64><<<dim3(1, 108), 256, 0, stream>>>(Bbuf, Wth, Wtl, bi2, h2, nullptr, N, 832, 64);

  // ---- spline layer 3 (64 -> 128), Kd = 1664 ----
  split_transpose_kernel<<<dim3(4, 50), tb32, 0, stream>>>(w3, Wth, Wtl, 1600, 128, 1664, 0);
  split_transpose_kernel<<<dim3(4, 2),  tb32, 0, stream>>>(r3, Wth, Wtl, 64, 128, 1664, 1600);
  b_build_kernel<<<N, 256, 26 * 64 * 4, stream>>>(h2, ecol, ew, ek, rowptr, csr, deginv, Bbuf, 64);
  gemm_x3_kernel<128><<<dim3(1, 108), 256, 0, stream>>>(Bbuf, Wth, Wtl, bi3, h3, nullptr, N, 1664, 128);

  // ---- stage 4: h4 = elu(h3 @ W1 + b1), written as bf16 ----
  split_transpose_kernel<<<dim3(8, 4), tb32, 0, stream>>>(W1, Wth, Wtl, 128, 256, 128, 0);
  gemm_x3_kernel<128><<<dim3(2, 108), 256, 0, stream>>>(h3, Wth, Wtl, b1, nullptr, h4b, N, 128, 256);

  // ---- W2 -> bf16 transposed ----
  w2_cast_transpose_kernel<<<dim3(216, 8), dim3(32, 8), 0, stream>>>(W2, W2t, 256, N);

  // ---- logits = h4 @ W2 + b2 (bf16 MFMA, f32 out into d_out) ----
  gemm_bf16_mfma_kernel<<<dim3(54, 54), 256, 0, stream>>>(h4b, W2t, b2, (float*)d_out, N, N);

  // ---- in-place log-softmax over rows ----
  log_softmax_kernel<<<N, 256, (size_t)N * 4, stream>>>((float*)d_out, N);

  (void)in_sizes; (void)n_in; (void)out_size; (void)ws_size;
}

// Round 3
// 305.266 us; speedup vs baseline: 2.8968x; 1.4153x over previous
//
#include <hip/hip_runtime.h>
#include <hip/hip_bf16.h>

#define NND 6890
#define NED 41340

typedef __bf16 bf16x8 __attribute__((ext_vector_type(8)));
typedef float f32x4 __attribute__((ext_vector_type(4)));
typedef unsigned short u16x4 __attribute__((ext_vector_type(4)));
typedef unsigned short u16x8 __attribute__((ext_vector_type(8)));

__device__ inline unsigned short f32_bf16(float f) {
  unsigned int u = __float_as_uint(f);
  unsigned int r = (u + 0x7FFFu + ((u >> 16) & 1u)) >> 16;
  return (unsigned short)r;
}
__device__ inline void split2(float v, unsigned short& hi, unsigned short& lo) {
  unsigned short h = f32_bf16(v);
  float hf = __uint_as_float((unsigned int)h << 16);
  hi = h;
  lo = f32_bf16(v - hf);
}
__device__ inline float elu_f(float v) { return v > 0.f ? v : (expf(v) - 1.f); }

__device__ __forceinline__ void gload_lds16(const void* g, void* l) {
  __builtin_amdgcn_global_load_lds((const __attribute__((address_space(1))) void*)g,
                                   (__attribute__((address_space(3))) void*)l, 16, 0, 0);
}

__global__ void zero_int_kernel(int* p, int n) {
  int i = blockIdx.x * blockDim.x + threadIdx.x;
  if (i < n) p[i] = 0;
}

__global__ void edge_prep_kernel(const int* __restrict__ erow, const float* __restrict__ pseudo,
                                 float* __restrict__ ew, int* __restrict__ ek,
                                 int* __restrict__ deg, int E) {
  int e = blockIdx.x * blockDim.x + threadIdx.x;
  if (e >= E) return;
  float p0 = pseudo[2 * e + 0] * 4.0f;
  float p1 = pseudo[2 * e + 1] * 4.0f;
  int i0 = (int)floorf(p0); i0 = i0 < 0 ? 0 : (i0 > 3 ? 3 : i0);
  int i1 = (int)floorf(p1); i1 = i1 < 0 ? 0 : (i1 > 3 ? 3 : i1);
  float f0 = p0 - (float)i0, f1 = p1 - (float)i1;
  ew[4 * e + 0] = (1.f - f0) * (1.f - f1);
  ew[4 * e + 1] = f0 * (1.f - f1);
  ew[4 * e + 2] = (1.f - f0) * f1;
  ew[4 * e + 3] = f0 * f1;
  int b = i0 + 5 * i1;
  ek[4 * e + 0] = b; ek[4 * e + 1] = b + 1; ek[4 * e + 2] = b + 5; ek[4 * e + 3] = b + 6;
  atomicAdd(&deg[erow[e]], 1);
}

__global__ void scan_kernel(const int* __restrict__ deg, int* __restrict__ rowptr,
                            int* __restrict__ cursor, float* __restrict__ deginv, int n) {
  __shared__ int part[1024];
  int t = threadIdx.x;
  int CH = (n + 1023) >> 10;
  int base = t * CH;
  int s = 0;
  for (int j = 0; j < CH; ++j) { int i = base + j; if (i < n) s += deg[i]; }
  part[t] = s;
  __syncthreads();
  for (int off = 1; off < 1024; off <<= 1) {
    int v = (t >= off) ? part[t - off] : 0;
    __syncthreads();
    part[t] += v;
    __syncthreads();
  }
  int run = (t == 0) ? 0 : part[t - 1];
  for (int j = 0; j < CH; ++j) {
    int i = base + j;
    if (i < n) {
      rowptr[i] = run; cursor[i] = run;
      int d = deg[i];
      deginv[i] = 1.0f / fmaxf((float)d, 1.0f);
      run += d;
    }
  }
  if (t == 1023) rowptr[n] = part[1023];
}

__global__ void csr_fill_kernel(const int* __restrict__ erow, int* __restrict__ cursor,
                                int* __restrict__ csr, int E) {
  int e = blockIdx.x * blockDim.x + threadIdx.x;
  if (e >= E) return;
  int slot = atomicAdd(&cursor[erow[e]], 1);
  csr[slot] = e;
}

// B[r, k*Fin+i] = deginv[r] * sum_{edges into r} w[e,s(k)] * x[col[e], i]; last Fin cols = x[r]
__global__ void b_build_kernel(const float* __restrict__ x, const int* __restrict__ ecol,
                               const float* __restrict__ ew, const int* __restrict__ ek,
                               const int* __restrict__ rowptr, const int* __restrict__ csr,
                               const float* __restrict__ deginv,
                               float* __restrict__ B, int Fin) {
  extern __shared__ float lds[];  // 26*Fin floats
  int r = blockIdx.x;
  int T = blockDim.x;  // 4*Fin
  int tid = threadIdx.x;
  int nb = 25 * Fin;
  for (int j = tid; j < nb; j += T) lds[j] = 0.f;
  if (tid < Fin) lds[nb + tid] = x[(size_t)r * Fin + tid];
  __syncthreads();
  int p0 = rowptr[r], p1 = rowptr[r + 1];
  int s = tid / Fin;
  int i = tid - s * Fin;
  for (int p = p0; p < p1; ++p) {
    int e = csr[p];
    int c = ecol[e];
    float wv = ew[4 * e + s];
    int k = ek[4 * e + s];
    float xv = x[(size_t)c * Fin + i];
    lds[k * Fin + i] += wv * xv;
    __syncthreads();
  }
  float dinv = deginv[r];
  int tot = nb + Fin;
  for (int j = tid; j < tot; j += T) {
    float v = lds[j];
    if (j < nb) v *= dinv;
    B[(size_t)r * tot + j] = v;
  }
}

// All weight splits (hi/lo bf16, transposed to [F, ldt]) in one kernel.
__global__ void weights_prep_kernel(const float* __restrict__ W_lin, const float* __restrict__ w1,
                                    const float* __restrict__ r1, const float* __restrict__ w2,
                                    const float* __restrict__ r2, const float* __restrict__ w3,
                                    const float* __restrict__ r3, const float* __restrict__ W1,
                                    unsigned short* __restrict__ Th, unsigned short* __restrict__ Tl) {
  const int tstart[9] = {0, 17, 30, 31, 81, 83, 283, 291, 323};
  const int jK[8]    = {544, 400, 16, 800, 32, 1600, 64, 128};
  const int jF[8]    = {16, 32, 32, 64, 64, 128, 128, 256};
  const int jldt[8]  = {544, 416, 416, 832, 832, 1664, 1664, 128};
  const int jkoff[8] = {0, 0, 400, 0, 800, 0, 1600, 0};
  const int jdst[8]  = {0, 8704, 8704, 22016, 22016, 75264, 75264, 288256};
  int b = blockIdx.x;
  int job = 0;
  while (job < 7 && b >= tstart[job + 1]) ++job;
  int t = b - tstart[job];
  int fxc = (jF[job] + 31) >> 5;
  int kt = t / fxc, ft = t % fxc;
  const float* src;
  switch (job) {
    case 0: src = W_lin; break;
    case 1: src = w1; break;
    case 2: src = r1; break;
    case 3: src = w2; break;
    case 4: src = r2; break;
    case 5: src = w3; break;
    case 6: src = r3; break;
    default: src = W1; break;
  }
  int K = jK[job], F = jF[job], ldt = jldt[job], koff = jkoff[job];
  unsigned short* th = Th + jdst[job];
  unsigned short* tl = Tl + jdst[job];
  int k0 = kt * 32, c0 = ft * 32;
  __shared__ float tbuf[32][33];
  int tx = threadIdx.x & 31, ty = threadIdx.x >> 5;  // 32 x 8
  for (int j = ty; j < 32; j += 8) {
    int gk = k0 + j, gc = c0 + tx;
    tbuf[j][tx] = (gk < K && gc < F) ? src[(size_t)gk * F + gc] : 0.f;
  }
  __syncthreads();
  for (int j = ty; j < 32; j += 8) {
    int gc = c0 + j, gk = k0 + tx;
    if (gc < F && gk < K) {
      unsigned short h, lo2;
      split2(tbuf[tx][j], h, lo2);
      th[(size_t)gc * ldt + koff + gk] = h;
      tl[(size_t)gc * ldt + koff + gk] = lo2;
    }
  }
}

// Partial GEMM (bf16x3 split) over K-slice z: P[z][M][F] = A @ W (no bias/elu).
template <int BN>
__global__ __launch_bounds__(256) void gemm_x3_partial_kernel(
    const float* __restrict__ A, const unsigned short* __restrict__ Wth,
    const unsigned short* __restrict__ Wtl, float* __restrict__ P,
    int M, int Kd, int F, int KS) {
  constexpr int BK = 32;
  constexpr int NF = BN / 16;
  constexpr int WU = (BK * BN) / 4;
  constexpr int WREP = (WU + 255) / 256;
  __shared__ __align__(16) unsigned short Ah[2][64][40];
  __shared__ __align__(16) unsigned short Al[2][64][40];
  __shared__ __align__(16) unsigned short Wh[2][BN][40];
  __shared__ __align__(16) unsigned short Wl[2][BN][40];
  int tid = threadIdx.x;
  int wave = tid >> 6, lane = tid & 63;
  int g = lane >> 4, r = lane & 15;
  int row0 = blockIdx.y * 64;
  int col0 = blockIdx.x * BN;
  int z = blockIdx.z;
  int nt = Kd >> 5;
  int ta = z * nt / KS, tb = (z + 1) * nt / KS;

  f32x4 acc[NF];
#pragma unroll
  for (int n = 0; n < NF; ++n)
#pragma unroll
    for (int q = 0; q < 4; ++q) acc[n][q] = 0.f;

  f32x4 ra[2];
  u16x4 rwh[WREP], rwl[WREP];

  auto loadTiles = [&](int kb) {
#pragma unroll
    for (int rep = 0; rep < 2; ++rep) {
      int u = tid + rep * 256;
      int rr = u >> 3, kq = (u & 7) * 4;
      int gr = row0 + rr;
      f32x4 v = {0.f, 0.f, 0.f, 0.f};
      if (gr < M) v = *(const f32x4*)(A + (size_t)gr * Kd + kb + kq);
      ra[rep] = v;
    }
#pragma unroll
    for (int rep = 0; rep < WREP; ++rep) {
      int u = tid + rep * 256;
      if (u < WU) {
        int cc = u >> 3, kq = (u & 7) * 4;
        rwh[rep] = *(const u16x4*)(Wth + (size_t)(col0 + cc) * Kd + kb + kq);
        rwl[rep] = *(const u16x4*)(Wtl + (size_t)(col0 + cc) * Kd + kb + kq);
      }
    }
  };
  auto writeLDS = [&](int buf) {
#pragma unroll
    for (int rep = 0; rep < 2; ++rep) {
      int u = tid + rep * 256;
      int rr = u >> 3, kq = (u & 7) * 4;
      u16x4 h, l;
#pragma unroll
      for (int j = 0; j < 4; ++j) {
        unsigned short hh, ll;
        split2(ra[rep][j], hh, ll);
        h[j] = hh; l[j] = ll;
      }
      *(u16x4*)&Ah[buf][rr][kq] = h;
      *(u16x4*)&Al[buf][rr][kq] = l;
    }
#pragma unroll
    for (int rep = 0; rep < WREP; ++rep) {
      int u = tid + rep * 256;
      if (u < WU) {
        int cc = u >> 3, kq = (u & 7) * 4;
        *(u16x4*)&Wh[buf][cc][kq] = rwh[rep];
        *(u16x4*)&Wl[buf][cc][kq] = rwl[rep];
      }
    }
  };

  int n = tb - ta;
  loadTiles(ta * BK);
  writeLDS(0);
  __syncthreads();
  for (int tt = 0; tt < n; ++tt) {
    int cur = tt & 1;
    if (tt + 1 < n) loadTiles((ta + tt + 1) * BK);
    bf16x8 fah = *(const bf16x8*)&Ah[cur][wave * 16 + r][g * 8];
    bf16x8 fal = *(const bf16x8*)&Al[cur][wave * 16 + r][g * 8];
#pragma unroll
    for (int nn = 0; nn < NF; ++nn) {
      bf16x8 fbh = *(const bf16x8*)&Wh[cur][nn * 16 + r][g * 8];
      bf16x8 fbl = *(const bf16x8*)&Wl[cur][nn * 16 + r][g * 8];
      acc[nn] = __builtin_amdgcn_mfma_f32_16x16x32_bf16(fah, fbh, acc[nn], 0, 0, 0);
      acc[nn] = __builtin_amdgcn_mfma_f32_16x16x32_bf16(fal, fbh, acc[nn], 0, 0, 0);
      acc[nn] = __builtin_amdgcn_mfma_f32_16x16x32_bf16(fah, fbl, acc[nn], 0, 0, 0);
    }
    if (tt + 1 < n) writeLDS(cur ^ 1);
    __syncthreads();
  }
#pragma unroll
  for (int nn = 0; nn < NF; ++nn) {
    int gc = col0 + nn * 16 + r;
#pragma unroll
    for (int q = 0; q < 4; ++q) {
      int gr = row0 + wave * 16 + g * 4 + q;
      if (gr < M) P[((size_t)z * M + gr) * F + gc] = acc[nn][q];
    }
  }
}

// out = elu(sum_z P[z] + bias); f32 or bf16 out
__global__ __launch_bounds__(256) void combine_elu_kernel(
    const float* __restrict__ P, const float* __restrict__ bias,
    float* __restrict__ outF, unsigned short* __restrict__ outB,
    int M, int F, int KS) {
  int i4 = blockIdx.x * 256 + threadIdx.x;
  int fv = F >> 2;
  int total = M * fv;
  if (i4 >= total) return;
  int gr = i4 / fv, c4 = (i4 - gr * fv) * 4;
  f32x4 s = {0.f, 0.f, 0.f, 0.f};
  for (int z = 0; z < KS; ++z)
    s += *(const f32x4*)(P + ((size_t)z * M + gr) * F + c4);
  f32x4 bv = *(const f32x4*)(bias + c4);
#pragma unroll
  for (int j = 0; j < 4; ++j) s[j] = elu_f(s[j] + bv[j]);
  if (outB) {
    u16x4 o;
#pragma unroll
    for (int j = 0; j < 4; ++j) o[j] = f32_bf16(s[j]);
    *(u16x4*)(outB + (size_t)gr * F + c4) = o;
  } else {
    *(f32x4*)(outF + (size_t)gr * F + c4) = s;
  }
}

// W2 [K=256, N] f32  ->  Wt [N, K] bf16
__global__ void w2_cast_transpose_kernel(const float* __restrict__ W2,
                                         unsigned short* __restrict__ Wt, int K, int N) {
  __shared__ float t[32][33];
  int c0 = blockIdx.x * 32, k0 = blockIdx.y * 32;
  int tx = threadIdx.x, ty = threadIdx.y;  // 32 x 8
  for (int j = ty; j < 32; j += 8) {
    int gk = k0 + j, gc = c0 + tx;
    t[j][tx] = (gk < K && gc < N) ? W2[(size_t)gk * N + gc] : 0.f;
  }
  __syncthreads();
  for (int j = ty; j < 32; j += 8) {
    int gc = c0 + j, gk = k0 + tx;
    if (gc < N && gk < K) Wt[(size_t)gc * K + gk] = f32_bf16(t[tx][j]);
  }
}

// C[M,N] = A[M,256] @ Bt[N,256]^T + bias. Full-K LDS residency, XOR-swizzled,
// global_load_lds staging, swapped-operand MFMA for f32x4 row-contiguous stores.
__global__ __launch_bounds__(256) void gemm_final_kernel(
    const unsigned short* __restrict__ A, const unsigned short* __restrict__ Bt,
    const float* __restrict__ bias, float* __restrict__ C, int M, int N) {
  __shared__ __align__(16) unsigned short lds[2][64][256];  // [0]=A rows, [1]=Bt rows; 64 KB
  int tid = threadIdx.x;
  int w = tid >> 6, l = tid & 63;
  int row0 = blockIdx.y * 64, col0 = blockIdx.x * 64;
  {
    int half = l >> 5;   // which row of the pair
    int c = l & 31;      // 16B chunk within row
#pragma unroll
    for (int i = 0; i < 8; ++i) {
      int rb = w * 16 + i * 2;       // wave-uniform row-pair base
      int rr = rb + half;            // per-lane tile row
      int gra = row0 + rr; if (gra >= M) gra = M - 1;
      int grb = col0 + rr; if (grb >= N) grb = N - 1;
      int cs = ((c ^ (rr & 7)) << 3);  // pre-swizzled source chunk (elements)
      gload_lds16(A + (size_t)gra * 256 + cs, &lds[0][rb][0]);
      gload_lds16(Bt + (size_t)grb * 256 + cs, &lds[1][rb][0]);
    }
  }
  __syncthreads();
  int wm = w >> 1, wn = w & 1;
  int g = l >> 4, r = l & 15;
  int rs = r & 7;
  f32x4 acc[2][2];
#pragma unroll
  for (int mi = 0; mi < 2; ++mi)
#pragma unroll
    for (int ni = 0; ni < 2; ++ni)
#pragma unroll
      for (int q = 0; q < 4; ++q) acc[mi][ni][q] = 0.f;
#pragma unroll
  for (int t = 0; t < 8; ++t) {
    int ck = ((4 * t + g) ^ rs) << 3;
    bf16x8 fa[2], fb[2];
#pragma unroll
    for (int mi = 0; mi < 2; ++mi)
      fa[mi] = *(const bf16x8*)&lds[0][wm * 32 + mi * 16 + r][ck];
#pragma unroll
    for (int ni = 0; ni < 2; ++ni)
      fb[ni] = *(const bf16x8*)&lds[1][wn * 32 + ni * 16 + r][ck];
#pragma unroll
    for (int mi = 0; mi < 2; ++mi)
#pragma unroll
      for (int ni = 0; ni < 2; ++ni)
        acc[mi][ni] = __builtin_amdgcn_mfma_f32_16x16x32_bf16(fb[ni], fa[mi], acc[mi][ni], 0, 0, 0);
  }
#pragma unroll
  for (int mi = 0; mi < 2; ++mi) {
    int gr = row0 + wm * 32 + mi * 16 + r;
    if (gr >= M) continue;
    float* crow = C + (size_t)gr * N;
#pragma unroll
    for (int ni = 0; ni < 2; ++ni) {
      int gc0 = col0 + wn * 32 + ni * 16 + g * 4;
      f32x4 v = acc[mi][ni];
      if (gc0 + 4 <= N) {
        f32x4 bv = *(const f32x4*)(bias + gc0);
        v += bv;
        *(f32x4*)(crow + gc0) = v;
      } else {
#pragma unroll
        for (int q = 0; q < 4; ++q)
          if (gc0 + q < N) crow[gc0 + q] = v[q] + bias[gc0 + q];
      }
    }
  }
}

// in-place row log-softmax, vectorized; row staged in LDS (N floats)
__global__ __launch_bounds__(256) void log_softmax_kernel(float* __restrict__ out, int N) {
  extern __shared__ float row[];
  __shared__ float wred[4];
  const int NV = 1722;  // N/4 (N = 6890 = 4*1722 + 2)
  float* p = out + (size_t)blockIdx.x * N;
  int tid = threadIdx.x;
  float m = -1e30f;
  for (int c = tid; c < NV; c += 256) {
    f32x4 v = *(const f32x4*)(p + 4 * c);
    *(f32x4*)&row[4 * c] = v;
    m = fmaxf(fmaxf(fmaxf(v[0], v[1]), fmaxf(v[2], v[3])), m);
  }
  if (tid < 2) { float v = p[6888 + tid]; row[6888 + tid] = v; m = fmaxf(m, v); }
  for (int off = 32; off; off >>= 1) m = fmaxf(m, __shfl_xor(m, off));
  if ((tid & 63) == 0) wred[tid >> 6] = m;
  __syncthreads();
  m = fmaxf(fmaxf(wred[0], wred[1]), fmaxf(wred[2], wred[3]));
  float s = 0.f;
  for (int c = tid; c < NV; c += 256) {
    f32x4 v = *(const f32x4*)&row[4 * c];
    s += expf(v[0] - m) + expf(v[1] - m) + expf(v[2] - m) + expf(v[3] - m);
  }
  if (tid < 2) s += expf(row[6888 + tid] - m);
  for (int off = 32; off; off >>= 1) s += __shfl_xor(s, off);
  __syncthreads();
  if ((tid & 63) == 0) wred[tid >> 6] = s;
  __syncthreads();
  float lse = m + logf(wred[0] + wred[1] + wred[2] + wred[3]);
  for (int c = tid; c < NV; c += 256) {
    f32x4 v = *(const f32x4*)&row[4 * c];
#pragma unroll
    for (int j = 0; j < 4; ++j) v[j] -= lse;
    *(f32x4*)(p + 4 * c) = v;
  }
  if (tid < 2) p[6888 + tid] = row[6888 + tid] - lse;
}

extern "C" void kernel_launch(void* const* d_in, const int* in_sizes, int n_in,
                              void* d_out, int out_size, void* d_ws, size_t ws_size,
                              hipStream_t stream) {
  const int N = NND, E = NED;
  const float* x      = (const float*)d_in[0];
  const int*   ei     = (const int*)d_in[1];
  const float* pseudo = (const float*)d_in[2];
  const float* W_lin  = (const float*)d_in[3];
  const float* b_lin  = (const float*)d_in[4];
  const float* w1  = (const float*)d_in[5];
  const float* r1  = (const float*)d_in[6];
  const float* bi1 = (const float*)d_in[7];
  const float* w2  = (const float*)d_in[8];
  const float* r2  = (const float*)d_in[9];
  const float* bi2 = (const float*)d_in[10];
  const float* w3  = (const float*)d_in[11];
  const float* r3  = (const float*)d_in[12];
  const float* bi3 = (const float*)d_in[13];
  const float* W1  = (const float*)d_in[14];
  const float* b1  = (const float*)d_in[15];
  const float* W2  = (const float*)d_in[16];
  const float* b2  = (const float*)d_in[17];
  const int* erow = ei;
  const int* ecol = ei + E;

  // Scratch carved out of d_out (dead before the final GEMM overwrites all of d_out)
  char* scratch = (char*)d_out;
  size_t off = 0;
  auto alloc = [&](size_t bytes) -> void* {
    void* p = scratch + off;
    off = (off + bytes + 255) & ~(size_t)255;
    return p;
  };
  float* Bbuf   = (float*)alloc((size_t)N * 1664 * 4);
  float* h0     = (float*)alloc((size_t)N * 16 * 4);
  float* h1     = (float*)alloc((size_t)N * 32 * 4);
  float* h2     = (float*)alloc((size_t)N * 64 * 4);
  float* h3     = (float*)alloc((size_t)N * 128 * 4);
  unsigned short* Wth = (unsigned short*)alloc((size_t)321024 * 2);
  unsigned short* Wtl = (unsigned short*)alloc((size_t)321024 * 2);
  float* Pbuf   = (float*)alloc((size_t)4 * N * 128 * 4);  // also fits 2*N*256
  float* ew     = (float*)alloc((size_t)E * 4 * 4);
  int*   ek     = (int*)alloc((size_t)E * 4 * 4);
  int*   deg    = (int*)alloc((size_t)N * 4);
  float* deginv = (float*)alloc((size_t)N * 4);
  int*   rowptr = (int*)alloc((size_t)(N + 1) * 4);
  int*   cursor = (int*)alloc((size_t)N * 4);
  int*   csr    = (int*)alloc((size_t)E * 4);

  // Buffers alive during the final GEMM go in d_ws
  unsigned short* h4b = (unsigned short*)d_ws;                                 // N*256 bf16
  unsigned short* W2t = (unsigned short*)((char*)d_ws + (size_t)N * 256 * 2);  // N*256 bf16

  // ---- graph prep ----
  zero_int_kernel<<<(N + 255) / 256, 256, 0, stream>>>(deg, N);
  edge_prep_kernel<<<(E + 255) / 256, 256, 0, stream>>>(erow, pseudo, ew, ek, deg, E);
  scan_kernel<<<1, 1024, 0, stream>>>(deg, rowptr, cursor, deginv, N);
  csr_fill_kernel<<<(E + 255) / 256, 256, 0, stream>>>(erow, cursor, csr, E);

  // ---- all weight splits in one launch ----
  weights_prep_kernel<<<323, 256, 0, stream>>>(W_lin, w1, r1, w2, r2, w3, r3, W1, Wth, Wtl);

  auto cgrid = [](int M_, int F_) { return dim3((M_ * (F_ / 4) + 255) / 256); };

  // ---- stage 0: h0 = elu(x @ W_lin + b_lin) ----
  gemm_x3_partial_kernel<16><<<dim3(1, 108, 4), 256, 0, stream>>>(x, Wth + 0, Wtl + 0, Pbuf, N, 544, 16, 4);
  combine_elu_kernel<<<cgrid(N, 16), 256, 0, stream>>>(Pbuf, b_lin, h0, nullptr, N, 16, 4);

  // ---- spline layer 1 (16 -> 32), Kd = 416 ----
  b_build_kernel<<<N, 64, 26 * 16 * 4, stream>>>(h0, ecol, ew, ek, rowptr, csr, deginv, Bbuf, 16);
  gemm_x3_partial_kernel<32><<<dim3(1, 108, 4), 256, 0, stream>>>(Bbuf, Wth + 8704, Wtl + 8704, Pbuf, N, 416, 32, 4);
  combine_elu_kernel<<<cgrid(N, 32), 256, 0, stream>>>(Pbuf, bi1, h1, nullptr, N, 32, 4);

  // ---- spline layer 2 (32 -> 64), Kd = 832 ----
  b_build_kernel<<<N, 128, 26 * 32 * 4, stream>>>(h1, ecol, ew, ek, rowptr, csr, deginv, Bbuf, 32);
  gemm_x3_partial_kernel<64><<<dim3(1, 108, 4), 256, 0, stream>>>(Bbuf, Wth + 22016, Wtl + 22016, Pbuf, N, 832, 64, 4);
  combine_elu_kernel<<<cgrid(N, 64), 256, 0, stream>>>(Pbuf, bi2, h2, nullptr, N, 64, 4);

  // ---- spline layer 3 (64 -> 128), Kd = 1664 ----
  b_build_kernel<<<N, 256, 26 * 64 * 4, stream>>>(h2, ecol, ew, ek, rowptr, csr, deginv, Bbuf, 64);
  gemm_x3_partial_kernel<128><<<dim3(1, 108, 4), 256, 0, stream>>>(Bbuf, Wth + 75264, Wtl + 75264, Pbuf, N, 1664, 128, 4);
  combine_elu_kernel<<<cgrid(N, 128), 256, 0, stream>>>(Pbuf, bi3, h3, nullptr, N, 128, 4);

  // ---- stage 4: h4 = elu(h3 @ W1 + b1) -> bf16 ----
  gemm_x3_partial_kernel<128><<<dim3(2, 108, 2), 256, 0, stream>>>(h3, Wth + 288256, Wtl + 288256, Pbuf, N, 128, 256, 2);
  combine_elu_kernel<<<cgrid(N, 256), 256, 0, stream>>>(Pbuf, b1, nullptr, h4b, N, 256, 2);

  // ---- W2 -> bf16 transposed ----
  w2_cast_transpose_kernel<<<dim3(216, 8), dim3(32, 8), 0, stream>>>(W2, W2t, 256, N);

  // ---- logits = h4 @ W2 + b2 ----
  gemm_final_kernel<<<dim3(108, 108), 256, 0, stream>>>(h4b, W2t, b2, (float*)d_out, N, N);

  // ---- in-place log-softmax over rows ----
  log_softmax_kernel<<<N, 256, (size_t)N * 4, stream>>>((float*)d_out, N);

  (void)in_sizes; (void)n_in; (void)out_size; (void)ws_size;
}